// Round 24
// baseline (3848.256 us; speedup 1.0000x reference)
//
#include <hip/hip_runtime.h>
#include <cstdio>
#include <cstddef>

enum { ACT_NONE = 0, ACT_LEAKY = 1, ACT_RELU = 2 };

typedef __attribute__((ext_vector_type(8))) short short8v;
typedef __attribute__((ext_vector_type(4))) float f32x4;

__device__ __forceinline__ float leakyf(float x) { return x > 0.f ? x : 0.01f * x; }

// order-preserving float -> uint encoding for atomicMax
__device__ __forceinline__ unsigned fenc(float f) {
    unsigned u = __float_as_uint(f);
    return (u & 0x80000000u) ? ~u : (u | 0x80000000u);
}
__device__ __forceinline__ float fdec(unsigned u) {
    return (u & 0x80000000u) ? __uint_as_float(u & 0x7FFFFFFFu) : __uint_as_float(~u);
}

// round-to-nearest bf16 (returns low 16 bits)
__device__ __forceinline__ unsigned bf16rtn(float x) {
    unsigned u = __float_as_uint(x);
    return (u + 0x7FFFu + ((u >> 16) & 1u)) >> 16;
}
__device__ __forceinline__ void split8(float4 a, float4 b, short8v& hi, short8v& lo) {
    const float v[8] = {a.x, a.y, a.z, a.w, b.x, b.y, b.z, b.w};
#pragma unroll
    for (int i = 0; i < 8; i++) {
        const unsigned hb = bf16rtn(v[i]);
        const float r = v[i] - __uint_as_float(hb << 16);
        hi[i] = (short)hb;
        lo[i] = (short)bf16rtn(r);
    }
}
__device__ __forceinline__ float eluf(float x) { return x > 0.f ? x : expm1f(x); }

// ---------------------------------------------------------------------------
// ONE kernel splitting ALL weights.
// ---------------------------------------------------------------------------
__global__ __launch_bounds__(256) void wsplit_all_k(
    const float* __restrict__ g0_Wih, const float* __restrict__ g0_Whh,
    const float* __restrict__ gWih,   const float* __restrict__ gWhh,
    const float* __restrict__ Wpn,    const float* __restrict__ W_et,
    const float* __restrict__ Wr1,    const float* __restrict__ Wr2,
    const float* __restrict__ W_e1,   const float* __restrict__ W_node,
    unsigned short* __restrict__ gwHi, unsigned short* __restrict__ gwLo,
    unsigned short* __restrict__ wtHi, unsigned short* __restrict__ wtLo,
    unsigned short* __restrict__ w96Hi, unsigned short* __restrict__ w96Lo)
{
    const int b = blockIdx.x, t = threadIdx.x;
    if (b < 1152) {
        const int slot = b / 96, inner = b % 96;
        const int i4 = (inner * 256 + t) * 4;
        if (i4 >= 98304) return;
        const float* Wih = slot == 0 ? g0_Wih : gWih + (size_t)(slot - 1) * 49152;
        const float* Whh = slot == 0 ? g0_Whh : gWhh + (size_t)(slot - 1) * 49152;
        const float* src = (i4 < 49152) ? (Wih + i4) : (Whh + (i4 - 49152));
        const float4 v = *(const float4*)src;
        const float vv[4] = {v.x, v.y, v.z, v.w};
        unsigned short h4[4], l4[4];
#pragma unroll
        for (int i = 0; i < 4; i++) {
            const unsigned hb = bf16rtn(vv[i]);
            const float r = vv[i] - __uint_as_float(hb << 16);
            h4[i] = (unsigned short)hb;
            l4[i] = (unsigned short)bf16rtn(r);
        }
        *(ushort4*)&gwHi[(size_t)slot * 98304 + i4] = make_ushort4(h4[0], h4[1], h4[2], h4[3]);
        *(ushort4*)&gwLo[(size_t)slot * 98304 + i4] = make_ushort4(l4[0], l4[1], l4[2], l4[3]);
    } else if (b < 2048) {
        const int q = b - 1152;
        const int slot = q / 64, inner = q % 64;
        const int idx = inner * 256 + t;
        if (idx >= 16384) return;
        const float* W = slot < 11 ? Wpn + (size_t)slot * 16384
                        : slot == 11 ? W_et : slot == 12 ? Wr1 : Wr2;
        const int k = idx >> 7, col = idx & 127;
        const float v = W[idx];
        const unsigned hb = bf16rtn(v);
        const float r = v - __uint_as_float(hb << 16);
        wtHi[(size_t)slot * 16384 + col * 128 + k] = (unsigned short)hb;
        wtLo[(size_t)slot * 16384 + col * 128 + k] = (unsigned short)bf16rtn(r);
    } else {
        const int q = b - 2048;
        const int slot = q / 48, inner = q % 48;
        const int idx = inner * 256 + t;
        if (idx >= 12288) return;
        const float* W = slot == 0 ? W_e1 : W_node;
        const int K   = slot == 0 ? 86 : 74;
        const int col = idx / 96, k = idx - col * 96;
        const float v = (k < K) ? W[(size_t)k * 128 + col] : 0.f;
        const unsigned hb = bf16rtn(v);
        const float r = v - __uint_as_float(hb << 16);
        w96Hi[(size_t)slot * 12288 + idx] = (unsigned short)hb;
        w96Lo[(size_t)slot * 12288 + idx] = (unsigned short)bf16rtn(r);
    }
}

// ---------------------------------------------------------------------------
// FUSED GRU via bf16x3 MFMA, v6 = round-23 core + T14 async-stage split:
// h (pass-2 input) is PREFETCHED into registers before pass-1's barrier so
// its global-load latency hides under pass-1's 144 MFMAs; after the barrier
// only split+LDS-write remains. Otherwise identical (3-barrier two-stage,
// LDS-transpose dots, fused pass-3).
// ---------------------------------------------------------------------------
__global__ __launch_bounds__(512) void gru_fused_mfma_k(
    const float* __restrict__ cbuf, const unsigned short* __restrict__ whi,
    const unsigned short* __restrict__ wlo, const float* __restrict__ bih,
    const float* __restrict__ bhh, float* __restrict__ h,
    const float* __restrict__ wa, const float* __restrict__ wb,
    float* __restrict__ pd, float* __restrict__ ps,
    const unsigned short* __restrict__ w3hi, const unsigned short* __restrict__ w3lo,
    const float* __restrict__ b3, float* __restrict__ out3, int act3, int M)
{
    __shared__ __align__(16) char smem[64 * 132 * 4];   // 33792 B
    short (*lhi)[4][64][8] = (short(*)[4][64][8])smem;              // 16 KB
    short (*llo)[4][64][8] = (short(*)[4][64][8])(smem + 16384);    // 16 KB
    float (*fbuf)[132] = (float(*)[132])smem;                       // overlay

    const int t    = threadIdx.x;
    const int lane = t & 63;
    const int w    = t >> 6;
    const int rBase = blockIdx.x * 64;

    const int sRS = t >> 3, sQ = t & 7;
    const int sRow = rBase + sRS;
    const int sRT = sRS >> 4, sLrow = sRS & 15;

    auto stage = [&](const float* __restrict__ A, bool doElu) {
#pragma unroll
        for (int half = 0; half < 2; half++) {
            const int k0 = sQ * 16 + half * 8;
            const int kc = k0 >> 5;
            const int g  = (k0 & 31) >> 3;
            float4 f0 = make_float4(0.f, 0.f, 0.f, 0.f);
            float4 f1 = make_float4(0.f, 0.f, 0.f, 0.f);
            if (sRow < M) {
                f0 = *(const float4*)&A[(size_t)sRow * 128 + k0];
                f1 = *(const float4*)&A[(size_t)sRow * 128 + k0 + 4];
                if (doElu) {
                    f0.x = eluf(f0.x); f0.y = eluf(f0.y); f0.z = eluf(f0.z); f0.w = eluf(f0.w);
                    f1.x = eluf(f1.x); f1.y = eluf(f1.y); f1.z = eluf(f1.z); f1.w = eluf(f1.w);
                }
            }
            short8v h8, l8;
            split8(f0, f1, h8, l8);
            *(short8v*)&lhi[sRT][kc][sLrow + g * 16][0] = h8;
            *(short8v*)&llo[sRT][kc][sLrow + g * 16][0] = l8;
        }
    };

    f32x4 accr[4], accz[4], accig[4], acchg[4];
#pragma unroll
    for (int rt = 0; rt < 4; rt++) {
        accr[rt]  = (f32x4){0.f, 0.f, 0.f, 0.f};
        accz[rt]  = (f32x4){0.f, 0.f, 0.f, 0.f};
        accig[rt] = (f32x4){0.f, 0.f, 0.f, 0.f};
        acchg[rt] = (f32x4){0.f, 0.f, 0.f, 0.f};
    }

    const int cw   = w * 16 + (lane & 15);   // gate-col [0,128)
    const int koff = (lane >> 4) * 8;

    // ---- stage elu(c); prefetch h into regs (latency hides under pass 1) ----
    stage(cbuf, true);
    float4 hpre[2][2];
#pragma unroll
    for (int half = 0; half < 2; half++) {
        const int k0 = sQ * 16 + half * 8;
        if (sRow < M) {
            hpre[half][0] = *(const float4*)&h[(size_t)sRow * 128 + k0];
            hpre[half][1] = *(const float4*)&h[(size_t)sRow * 128 + k0 + 4];
        } else {
            hpre[half][0] = make_float4(0.f, 0.f, 0.f, 0.f);
            hpre[half][1] = make_float4(0.f, 0.f, 0.f, 0.f);
        }
    }
    __syncthreads();

    // ---- pass 1: elu(c) @ Wih.T ----
#pragma unroll
    for (int kc = 0; kc < 4; kc++) {
        short8v bh[3], bl[3];
#pragma unroll
        for (int g = 0; g < 3; g++) {
            const size_t off = (size_t)(g * 128 + cw) * 128 + kc * 32 + koff;
            bh[g] = *(const short8v*)&whi[off];
            bl[g] = *(const short8v*)&wlo[off];
        }
#pragma unroll
        for (int rt = 0; rt < 4; rt++) {
            const short8v ah = *(const short8v*)&lhi[rt][kc][lane][0];
            const short8v al = *(const short8v*)&llo[rt][kc][lane][0];
            accr[rt]  = __builtin_amdgcn_mfma_f32_16x16x32_bf16(ah, bh[0], accr[rt], 0, 0, 0);
            accr[rt]  = __builtin_amdgcn_mfma_f32_16x16x32_bf16(al, bh[0], accr[rt], 0, 0, 0);
            accr[rt]  = __builtin_amdgcn_mfma_f32_16x16x32_bf16(ah, bl[0], accr[rt], 0, 0, 0);
            accz[rt]  = __builtin_amdgcn_mfma_f32_16x16x32_bf16(ah, bh[1], accz[rt], 0, 0, 0);
            accz[rt]  = __builtin_amdgcn_mfma_f32_16x16x32_bf16(al, bh[1], accz[rt], 0, 0, 0);
            accz[rt]  = __builtin_amdgcn_mfma_f32_16x16x32_bf16(ah, bl[1], accz[rt], 0, 0, 0);
            accig[rt] = __builtin_amdgcn_mfma_f32_16x16x32_bf16(ah, bh[2], accig[rt], 0, 0, 0);
            accig[rt] = __builtin_amdgcn_mfma_f32_16x16x32_bf16(al, bh[2], accig[rt], 0, 0, 0);
            accig[rt] = __builtin_amdgcn_mfma_f32_16x16x32_bf16(ah, bl[2], accig[rt], 0, 0, 0);
        }
    }
    __syncthreads();   // all waves done reading LDS before re-stage

    // ---- write prefetched h to LDS (no global latency here) ----
#pragma unroll
    for (int half = 0; half < 2; half++) {
        const int k0 = sQ * 16 + half * 8;
        const int kc = k0 >> 5;
        const int g  = (k0 & 31) >> 3;
        short8v h8, l8;
        split8(hpre[half][0], hpre[half][1], h8, l8);
        *(short8v*)&lhi[sRT][kc][sLrow + g * 16][0] = h8;
        *(short8v*)&llo[sRT][kc][sLrow + g * 16][0] = l8;
    }
    __syncthreads();

    // ---- pass 2: h @ Whh.T (r,z accumulate into same accs) ----
#pragma unroll
    for (int kc = 0; kc < 4; kc++) {
        short8v bh[3], bl[3];
#pragma unroll
        for (int g = 0; g < 3; g++) {
            const size_t off = (size_t)(384 + g * 128 + cw) * 128 + kc * 32 + koff;
            bh[g] = *(const short8v*)&whi[off];
            bl[g] = *(const short8v*)&wlo[off];
        }
#pragma unroll
        for (int rt = 0; rt < 4; rt++) {
            const short8v ah = *(const short8v*)&lhi[rt][kc][lane][0];
            const short8v al = *(const short8v*)&llo[rt][kc][lane][0];
            accr[rt]  = __builtin_amdgcn_mfma_f32_16x16x32_bf16(ah, bh[0], accr[rt], 0, 0, 0);
            accr[rt]  = __builtin_amdgcn_mfma_f32_16x16x32_bf16(al, bh[0], accr[rt], 0, 0, 0);
            accr[rt]  = __builtin_amdgcn_mfma_f32_16x16x32_bf16(ah, bl[0], accr[rt], 0, 0, 0);
            accz[rt]  = __builtin_amdgcn_mfma_f32_16x16x32_bf16(ah, bh[1], accz[rt], 0, 0, 0);
            accz[rt]  = __builtin_amdgcn_mfma_f32_16x16x32_bf16(al, bh[1], accz[rt], 0, 0, 0);
            accz[rt]  = __builtin_amdgcn_mfma_f32_16x16x32_bf16(ah, bl[1], accz[rt], 0, 0, 0);
            acchg[rt] = __builtin_amdgcn_mfma_f32_16x16x32_bf16(ah, bh[2], acchg[rt], 0, 0, 0);
            acchg[rt] = __builtin_amdgcn_mfma_f32_16x16x32_bf16(al, bh[2], acchg[rt], 0, 0, 0);
            acchg[rt] = __builtin_amdgcn_mfma_f32_16x16x32_bf16(ah, bl[2], acchg[rt], 0, 0, 0);
        }
    }

    // ---- gate epilogue ----
    const bool post = (wa != nullptr) || (w3hi != nullptr);
    const float br_  = bih[cw] + bhh[cw];
    const float bz_  = bih[128 + cw] + bhh[128 + cw];
    const float big_ = bih[256 + cw];
    const float bhg_ = bhh[256 + cw];
    if (post) __syncthreads();   // MFMA LDS reads done before fbuf overlay
#pragma unroll
    for (int rt = 0; rt < 4; rt++) {
        const int lr0 = rt * 16 + ((lane >> 4) << 2);
#pragma unroll
        for (int i = 0; i < 4; i++) {
            const int row = rBase + lr0 + i;
            const bool ok = (row < M);
            float hnew = 0.f;
            if (ok) {
                const float hv = h[(size_t)row * 128 + cw];
                const float r  = 1.f / (1.f + expf(-(accr[rt][i] + br_)));
                const float z  = 1.f / (1.f + expf(-(accz[rt][i] + bz_)));
                const float nn = tanhf(accig[rt][i] + big_ + r * (acchg[rt][i] + bhg_));
                hnew = fmaxf((1.f - z) * nn + z * hv, 0.f);
                h[(size_t)row * 128 + cw] = hnew;
            }
            if (post) fbuf[lr0 + i][cw] = hnew;
        }
    }
    if (!post) return;
    __syncthreads();

    // ---- fused node-dots (first 64 threads) ----
    if (wa && t < 64 && rBase + t < M) {
        float accd = 0.f, accs = 0.f;
        for (int cc = 0; cc < 128; cc++) {
            const float hv = fbuf[t][cc];
            accd = fmaf(hv, wa[cc], accd);
            accs = fmaf(hv, wb[cc], accs);
        }
        pd[rBase + t] = accd;
        ps[rBase + t] = accs;
    }

    // ---- pass 3: out3 = act3(h_new @ W3 + b3), h_new re-staged from LDS ----
    if (w3hi) {
        float4 rv[2][2];
#pragma unroll
        for (int half = 0; half < 2; half++) {
            const int k0 = sQ * 16 + half * 8;
            rv[half][0] = *(const float4*)&fbuf[sRS][k0];
            rv[half][1] = *(const float4*)&fbuf[sRS][k0 + 4];
        }
        __syncthreads();   // fbuf reads done before lhi/llo overwrite
#pragma unroll
        for (int half = 0; half < 2; half++) {
            const int k0 = sQ * 16 + half * 8;
            const int kc = k0 >> 5;
            const int g  = (k0 & 31) >> 3;
            short8v h8, l8;
            split8(rv[half][0], rv[half][1], h8, l8);
            *(short8v*)&lhi[sRT][kc][sLrow + g * 16][0] = h8;
            *(short8v*)&llo[sRT][kc][sLrow + g * 16][0] = l8;
        }
        __syncthreads();

        f32x4 acc3[4];
#pragma unroll
        for (int rt = 0; rt < 4; rt++) acc3[rt] = (f32x4){0.f, 0.f, 0.f, 0.f};
#pragma unroll
        for (int kc = 0; kc < 4; kc++) {
            const size_t off = (size_t)cw * 128 + kc * 32 + koff;
            const short8v bh = *(const short8v*)&w3hi[off];
            const short8v bl = *(const short8v*)&w3lo[off];
#pragma unroll
            for (int rt = 0; rt < 4; rt++) {
                const short8v ah = *(const short8v*)&lhi[rt][kc][lane][0];
                const short8v al = *(const short8v*)&llo[rt][kc][lane][0];
                acc3[rt] = __builtin_amdgcn_mfma_f32_16x16x32_bf16(ah, bh, acc3[rt], 0, 0, 0);
                acc3[rt] = __builtin_amdgcn_mfma_f32_16x16x32_bf16(al, bh, acc3[rt], 0, 0, 0);
                acc3[rt] = __builtin_amdgcn_mfma_f32_16x16x32_bf16(ah, bl, acc3[rt], 0, 0, 0);
            }
        }
        const float b0 = b3[cw];
#pragma unroll
        for (int rt = 0; rt < 4; rt++) {
            const int r0 = rBase + rt * 16 + ((lane >> 4) << 2);
#pragma unroll
            for (int i = 0; i < 4; i++) {
                const int row = r0 + i;
                if (row >= M) continue;
                float v = acc3[rt][i] + b0;
                if (act3 == ACT_LEAKY)      v = v > 0.f ? v : 0.01f * v;
                else if (act3 == ACT_RELU)  v = fmaxf(v, 0.f);
                out3[(size_t)row * 128 + cw] = v;
            }
        }
    }
}

// ---------------------------------------------------------------------------
// Single-output MFMA GEMM (K=128, NC=128), bf16x3 (round-13 verified).
// ---------------------------------------------------------------------------
__global__ __launch_bounds__(512) void mfma128_k(
    const float* __restrict__ A, const unsigned short* __restrict__ whi,
    const unsigned short* __restrict__ wlo, const float* __restrict__ bias,
    float* __restrict__ C, int M, int actOut)
{
    __shared__ short lhi[4][4][64][8];
    __shared__ short llo[4][4][64][8];
    const int t    = threadIdx.x;
    const int lane = t & 63;
    const int w    = t >> 6;
    const int rBase = blockIdx.x * 64;

    {
        const int rS = t >> 3, q = t & 7;
        const int row = rBase + rS;
        const int rt = rS >> 4, lrow = rS & 15;
#pragma unroll
        for (int half = 0; half < 2; half++) {
            const int k0 = q * 16 + half * 8;
            const int kc = k0 >> 5;
            const int g  = (k0 & 31) >> 3;
            float4 f0 = make_float4(0.f, 0.f, 0.f, 0.f);
            float4 f1 = make_float4(0.f, 0.f, 0.f, 0.f);
            if (row < M) {
                f0 = *(const float4*)&A[(size_t)row * 128 + k0];
                f1 = *(const float4*)&A[(size_t)row * 128 + k0 + 4];
            }
            short8v h8, l8;
            split8(f0, f1, h8, l8);
            *(short8v*)&lhi[rt][kc][lrow + g * 16][0] = h8;
            *(short8v*)&llo[rt][kc][lrow + g * 16][0] = l8;
        }
    }
    __syncthreads();

    f32x4 acc[4];
#pragma unroll
    for (int rt = 0; rt < 4; rt++) acc[rt] = (f32x4){0.f, 0.f, 0.f, 0.f};

    const int cw   = w * 16 + (lane & 15);
    const int koff = (lane >> 4) * 8;

#pragma unroll
    for (int kc = 0; kc < 4; kc++) {
        const size_t off = (size_t)cw * 128 + kc * 32 + koff;
        const short8v bh = *(const short8v*)&whi[off];
        const short8v bl = *(const short8v*)&wlo[off];
#pragma unroll
        for (int rt = 0; rt < 4; rt++) {
            const short8v ah = *(const short8v*)&lhi[rt][kc][lane][0];
            const short8v al = *(const short8v*)&llo[rt][kc][lane][0];
            acc[rt] = __builtin_amdgcn_mfma_f32_16x16x32_bf16(ah, bh, acc[rt], 0, 0, 0);
            acc[rt] = __builtin_amdgcn_mfma_f32_16x16x32_bf16(al, bh, acc[rt], 0, 0, 0);
            acc[rt] = __builtin_amdgcn_mfma_f32_16x16x32_bf16(ah, bl, acc[rt], 0, 0, 0);
        }
    }

    const float b0 = bias[cw];
#pragma unroll
    for (int rt = 0; rt < 4; rt++) {
        const int r0 = rBase + rt * 16 + ((lane >> 4) << 2);
#pragma unroll
        for (int i = 0; i < 4; i++) {
            const int row = r0 + i;
            if (row >= M) continue;
            float v = acc[rt][i] + b0;
            if (actOut == ACT_LEAKY)      v = v > 0.f ? v : 0.01f * v;
            else if (actOut == ACT_RELU)  v = fmaxf(v, 0.f);
            C[(size_t)row * 128 + cw] = v;
        }
    }
}

// ---------------------------------------------------------------------------
// Gathered MFMA GEMM, K padded to 96. Modes (combinable):
//   writeC : C[row] = v
//   dotOut : dotOut[row] = v . dotW      (LDS transpose-reduce, no atomics)
//   ee     : CSR-ordered fused softmax-scatter with SEGMENTED atomics
//            (ee/sd/dstI indexed by row directly; inputs pre-permuted)
// ---------------------------------------------------------------------------
__global__ __launch_bounds__(512) void mfma96_k(
    const float* __restrict__ A1, const float* __restrict__ A2,
    const int* __restrict__ idx, const int* __restrict__ idx2,
    const unsigned short* __restrict__ whi, const unsigned short* __restrict__ wlo,
    const float* __restrict__ bias, float* __restrict__ C,
    const float* __restrict__ dotW, float* __restrict__ dotOut,
    const float* __restrict__ ee, const float* __restrict__ sd,
    const int* __restrict__ dstI, float* __restrict__ cAtom,
    int writeC, int M, int K1, int actOut)
{
    __shared__ __align__(16) char smem[64 * 130 * 4];   // 33280 B
    short (*lhi)[3][64][8] = (short(*)[3][64][8])smem;              // 12288
    short (*llo)[3][64][8] = (short(*)[3][64][8])(smem + 12288);    // 12288
    float (*fbuf)[130] = (float(*)[130])smem;                       // overlay

    const int t    = threadIdx.x;
    const int lane = t & 63;
    const int w    = t >> 6;
    const int rBase = blockIdx.x * 64;

    {
        const int rS = t >> 3, q = t & 7;
        const int row = rBase + rS;
        const int rt = rS >> 4, lrow = rS & 15;
#pragma unroll
        for (int half = 0; half < 2; half++) {
            const int k0 = q * 16 + half * 8;
            if (k0 >= 96) continue;
            const int kc = k0 >> 5;
            const int g  = (k0 & 31) >> 3;
            float v[8] = {0.f, 0.f, 0.f, 0.f, 0.f, 0.f, 0.f, 0.f};
            if (row < M) {
                const int ar  = idx ? idx[row] : row;
                const int ar2 = idx2 ? idx2[row] : row;
                const float* __restrict__ a1 = A1 + (size_t)ar * K1;
#pragma unroll
                for (int j = 0; j < 8; j++) {
                    const int k = k0 + j;
                    if (k < K1)                 v[j] = a1[k];
                    else if (A2 && k < K1 + 12) v[j] = A2[(size_t)ar2 * 12 + (k - K1)];
                }
            }
            short8v h8, l8;
            split8(make_float4(v[0], v[1], v[2], v[3]),
                   make_float4(v[4], v[5], v[6], v[7]), h8, l8);
            *(short8v*)&lhi[rt][kc][lrow + g * 16][0] = h8;
            *(short8v*)&llo[rt][kc][lrow + g * 16][0] = l8;
        }
    }
    __syncthreads();

    f32x4 acc[4];
#pragma unroll
    for (int rt = 0; rt < 4; rt++) acc[rt] = (f32x4){0.f, 0.f, 0.f, 0.f};

    const int cw   = w * 16 + (lane & 15);
    const int koff = (lane >> 4) * 8;

#pragma unroll
    for (int kc = 0; kc < 3; kc++) {
        const size_t off = (size_t)cw * 96 + kc * 32 + koff;
        const short8v bh = *(const short8v*)&whi[off];
        const short8v bl = *(const short8v*)&wlo[off];
#pragma unroll
        for (int rt = 0; rt < 4; rt++) {
            const short8v ah = *(const short8v*)&lhi[rt][kc][lane][0];
            const short8v al = *(const short8v*)&llo[rt][kc][lane][0];
            acc[rt] = __builtin_amdgcn_mfma_f32_16x16x32_bf16(ah, bh, acc[rt], 0, 0, 0);
            acc[rt] = __builtin_amdgcn_mfma_f32_16x16x32_bf16(al, bh, acc[rt], 0, 0, 0);
            acc[rt] = __builtin_amdgcn_mfma_f32_16x16x32_bf16(ah, bl, acc[rt], 0, 0, 0);
        }
    }

    const float b0 = bias[cw];
    const bool useF = (dotOut != nullptr) || (ee != nullptr);
    if (useF) __syncthreads();   // MFMA LDS reads done before fbuf overlay
#pragma unroll
    for (int rt = 0; rt < 4; rt++) {
        const int lr0 = rt * 16 + ((lane >> 4) << 2);
#pragma unroll
        for (int i = 0; i < 4; i++) {
            const int row = rBase + lr0 + i;
            const bool ok = (row < M);
            float v = acc[rt][i] + b0;
            if (actOut == ACT_LEAKY)      v = v > 0.f ? v : 0.01f * v;
            else if (actOut == ACT_RELU)  v = fmaxf(v, 0.f);
            if (ok && writeC) C[(size_t)row * 128 + cw] = v;
            if (ee) {
                float av = 0.f;
                if (ok) av = ee[row] / sd[dstI[row]] * v;
                fbuf[lr0 + i][cw] = av;
            } else if (dotOut) {
                fbuf[lr0 + i][cw] = ok ? v : 0.f;
            }
        }
    }
    if (ee) {
        __syncthreads();
        // segmented run-length reduce: thread owns col (t&127), rows (t>>7)*16..+15
        const int col = t & 127;
        const int r0  = (t >> 7) * 16;
        float acc2 = 0.f;
        int cur = -1;
        for (int j = 0; j < 16; j++) {
            const int row = rBase + r0 + j;
            if (row >= M) break;
            const int d = dstI[row];
            if (d != cur) {
                if (cur >= 0) atomicAdd(&cAtom[(size_t)cur * 128 + col], acc2);
                cur = d;
                acc2 = 0.f;
            }
            acc2 += fbuf[r0 + j][col];
        }
        if (cur >= 0) atomicAdd(&cAtom[(size_t)cur * 128 + col], acc2);
    } else if (dotOut) {
        __syncthreads();
        if (t < 64 && rBase + t < M) {
            float accd = 0.f;
            for (int cc = 0; cc < 128; cc++)
                accd = fmaf(fbuf[t][cc], dotW[cc], accd);
            dotOut[rBase + t] = accd;
        }
    }
}

// GetContext edge logits from precomputed pe: lg = leaky(pd[dst]+pe[e]+b2); atomicMax m
__global__ __launch_bounds__(256) void edge_lgc_k(
    const float* __restrict__ pd, const float* __restrict__ pe,
    const float* __restrict__ b2, const int* __restrict__ dst,
    float* __restrict__ lg, unsigned* __restrict__ m_u, int E)
{
    const int e = blockIdx.x * blockDim.x + threadIdx.x;
    if (e >= E) return;
    const int d = dst[e];
    const float v = leakyf(pd[d] + pe[e] + b2[0]);
    lg[e] = v;
    atomicMax(&m_u[d], fenc(v));
}

// ex = exp(lg - m[dst]); s[dst] += ex; lgS[einv[e]] = ex  (sorted-order copy)
__global__ __launch_bounds__(256) void edge_exp_k(
    const float* __restrict__ lg, const unsigned* __restrict__ m_u,
    float* __restrict__ s, const int* __restrict__ dst,
    const int* __restrict__ einv, float* __restrict__ lgS, int E)
{
    const int e = blockIdx.x * blockDim.x + threadIdx.x;
    if (e >= E) return;
    const int d = dst[e];
    const float ex = expf(lg[e] - fdec(m_u[d]));
    lgS[einv[e]] = ex;
    atomicAdd(&s[d], ex);
}

// permute bond rows into CSR (dst-sorted) order: bondS[p] = bond[eidx[p]]
__global__ __launch_bounds__(256) void bperm_k(
    const float* __restrict__ bond, const int* __restrict__ eidx,
    float* __restrict__ bondS, int E)
{
    const long long i = (long long)blockIdx.x * blockDim.x + threadIdx.x;
    if (i >= (long long)E * 12) return;
    const int p = (int)(i / 12), j = (int)(i - (long long)p * 12);
    bondS[i] = bond[(size_t)eidx[p] * 12 + j];
}

// ---------------------------------------------------------------------------
// CSR build: histogram -> exclusive scan -> fill (emits srcS/dstS/einv)
// ---------------------------------------------------------------------------
__global__ __launch_bounds__(256) void hist_k(
    const int* __restrict__ dst, unsigned* __restrict__ cnt, int E)
{
    const int e = blockIdx.x * blockDim.x + threadIdx.x;
    if (e < E) atomicAdd(&cnt[dst[e]], 1u);
}

__global__ __launch_bounds__(1024) void scan_k(
    const unsigned* __restrict__ cnt, int* __restrict__ rp, int N)
{
    __shared__ int wsum[16];
    __shared__ int carry;
    const int t = threadIdx.x, lane = t & 63, wid = t >> 6;
    if (t == 0) carry = 0;
    __syncthreads();
    for (int base = 0; base < N; base += 1024) {
        const int i = base + t;
        const int v = (i < N) ? (int)cnt[i] : 0;
        int x = v;
#pragma unroll
        for (int o = 1; o < 64; o <<= 1) {
            const int y = __shfl_up(x, o, 64);
            if (lane >= o) x += y;
        }
        if (lane == 63) wsum[wid] = x;
        __syncthreads();
        if (wid == 0) {
            const int wv = (lane < 16) ? wsum[lane] : 0;
            int wx = wv;
#pragma unroll
            for (int o = 1; o < 16; o <<= 1) {
                const int y = __shfl_up(wx, o, 64);
                if (lane >= o) wx += y;
            }
            if (lane < 16) wsum[lane] = wx - wv;   // exclusive wave offsets
        }
        __syncthreads();
        const int excl = carry + wsum[wid] + x - v;
        if (i < N) rp[i] = excl;
        __syncthreads();
        if (t == 1023) carry = excl + v;
        __syncthreads();
    }
    if (t == 0) rp[N] = carry;
}

__global__ __launch_bounds__(256) void fill_csr_k(
    const int* __restrict__ dst, const int* __restrict__ src,
    int* __restrict__ pos, int* __restrict__ eidx,
    int* __restrict__ srcS, int* __restrict__ dstS,
    int* __restrict__ einv, int E)
{
    const int e = blockIdx.x * blockDim.x + threadIdx.x;
    if (e < E) {
        const int d = dst[e];
        const int p = atomicAdd(&pos[d], 1);
        eidx[p] = e;
        srcS[p] = src[e];
        dstS[p] = d;
        einv[e] = p;
    }
}

// ---------------------------------------------------------------------------
// Fused per-node edge softmax + weighted gather (layers) -- standalone
// ---------------------------------------------------------------------------
__global__ __launch_bounds__(256) void layer_gather_k(
    const int* __restrict__ rp, const int* __restrict__ srcS,
    const float* __restrict__ pd, const float* __restrict__ ps,
    const float* __restrict__ bpe,
    const float* __restrict__ hp, float* __restrict__ c, int N)
{
    const int d = blockIdx.x * 4 + (threadIdx.x >> 6);
    const int l = threadIdx.x & 63;
    if (d >= N) return;
    const int beg = rp[d], end = rp[d + 1];
    float acc0 = 0.f, acc1 = 0.f;
    if (beg < end) {
        const float pdd = pd[d];
        const float b   = bpe[0];
        float m = -3.4e38f;
        for (int e = beg + l; e < end; e += 64)
            m = fmaxf(m, leakyf(pdd + ps[srcS[e]] + b));
#pragma unroll
        for (int o = 32; o; o >>= 1) m = fmaxf(m, __shfl_xor(m, o, 64));
        float s = 0.f;
        for (int e = beg + l; e < end; e += 64)
            s += expf(leakyf(pdd + ps[srcS[e]] + b) - m);
#pragma unroll
        for (int o = 32; o; o >>= 1) s += __shfl_xor(s, o, 64);
        const float inv = 1.f / s;
        for (int e = beg; e < end; ++e) {
            const int sr = srcS[e];                      // uniform -> broadcast
            const float a = expf(leakyf(pdd + ps[sr] + b) - m) * inv;
            const float2 v = *(const float2*)&hp[(size_t)sr * 128 + l * 2];
            acc0 = fmaf(a, v.x, acc0);
            acc1 = fmaf(a, v.y, acc1);
        }
    }
    *(float2*)&c[(size_t)d * 128 + l * 2] = make_float2(acc0, acc1);
}

// segmented mean readout (node_graph_ids sorted): one wave per graph
__global__ __launch_bounds__(256) void readout_mean_k(
    const float* __restrict__ x, const int* __restrict__ grp,
    float* __restrict__ out, int G)
{
    const int g = blockIdx.x * 4 + (threadIdx.x >> 6);
    const int l = threadIdx.x & 63;
    if (g >= G) return;
    const int beg = grp[g], end = grp[g + 1];
    float s0 = 0.f, s1 = 0.f;
    for (int r = beg; r < end; ++r) {
        const float2 v = *(const float2*)&x[(size_t)r * 128 + l * 2];
        s0 += v.x;
        s1 += v.y;
    }
    const float inv = 1.f / fmaxf((float)(end - beg), 1.f);
    *(float2*)&out[(size_t)g * 128 + l * 2] = make_float2(s0 * inv, s1 * inv);
}

// ---------------------------------------------------------------------------
extern "C" void kernel_launch(void* const* d_in, const int* in_sizes, int n_in,
                              void* d_out, int out_size, void* d_ws, size_t ws_size,
                              hipStream_t stream)
{
    const float* atom   = (const float*)d_in[0];
    const float* bond   = (const float*)d_in[1];
    const int*   src    = (const int*)d_in[2];
    const int*   dst    = (const int*)d_in[3];
    const int*   ngid   = (const int*)d_in[4];
    const float* W_node = (const float*)d_in[5];
    const float* b_node = (const float*)d_in[6];
    const float* W_e1   = (const float*)d_in[7];
    const float* b_e1   = (const float*)d_in[8];
    const float* W_e2   = (const float*)d_in[9];
    const float* b_e2   = (const float*)d_in[10];
    const float* W_et   = (const float*)d_in[11];
    const float* b_et   = (const float*)d_in[12];
    const float* g0_Wih = (const float*)d_in[13];
    const float* g0_bih = (const float*)d_in[14];
    const float* g0_Whh = (const float*)d_in[15];
    const float* g0_bhh = (const float*)d_in[16];
    const float* Wpe    = (const float*)d_in[17];
    const float* bpe    = (const float*)d_in[18];
    const float* Wpn    = (const float*)d_in[19];
    const float* bpn    = (const float*)d_in[20];
    const float* gWih   = (const float*)d_in[21];
    const float* gbih   = (const float*)d_in[22];
    const float* gWhh   = (const float*)d_in[23];
    const float* gbhh   = (const float*)d_in[24];
    const float* Wr1    = (const float*)d_in[25];
    const float* br1    = (const float*)d_in[26];
    const float* Wr2    = (const float*)d_in[27];
    const float* br2    = (const float*)d_in[28];

    const int N = in_sizes[0] / 74;
    const int E = in_sizes[1] / 12;
    const int G = out_size / 128;
    const int L = in_sizes[18];   // bpe is [L][1]

    char* w = (char*)d_ws;
    auto align256 = [](size_t b) { return (b + 255) & ~(size_t)255; };
    auto alloc = [&](size_t bytes) {
        void* p = (void*)w;
        w += align256(bytes);
        return p;
    };
    float*    h    = (float*)alloc((size_t)N * 128 * 4);
    float*    c    = (float*)alloc((size_t)N * 128 * 4);
    float*    hp   = (float*)alloc((size_t)N * 128 * 4);
    int*      rp   = (int*)alloc((size_t)(N + 1) * 4);
    int*      posb = (int*)alloc((size_t)N * 4);
    int*      eidx = (int*)alloc((size_t)E * 4);
    int*      srcS = (int*)alloc((size_t)E * 4);
    int*      dstS = (int*)alloc((size_t)E * 4);
    int*      einv = (int*)alloc((size_t)E * 4);
    float*    bondS= (float*)alloc((size_t)E * 12 * 4);
    float*    lgS  = (float*)alloc((size_t)E * 4);
    int*      grp  = (int*)alloc((size_t)(G + 1) * 4);
    // weight slots: GRU 12 x 98304, T128 14 x 16384, T96 2 x 12288
    unsigned short* gwHi  = (unsigned short*)alloc((size_t)12 * 98304 * 2);
    unsigned short* gwLo  = (unsigned short*)alloc((size_t)12 * 98304 * 2);
    unsigned short* wtHi  = (unsigned short*)alloc((size_t)14 * 16384 * 2);
    unsigned short* wtLo  = (unsigned short*)alloc((size_t)14 * 16384 * 2);
    unsigned short* w96Hi = (unsigned short*)alloc((size_t)2 * 12288 * 2);
    unsigned short* w96Lo = (unsigned short*)alloc((size_t)2 * 12288 * 2);
    float*    pd   = (float*)alloc((size_t)N * 4);
    float*    ps   = (float*)alloc((size_t)N * 4);
    unsigned* m_u  = (unsigned*)alloc((size_t)N * 4);
    float*    sden = (float*)alloc((size_t)N * 4);
    float*    pe   = (float*)alloc((size_t)E * 4);
    float*    lg   = (float*)alloc((size_t)E * 4);
    if ((size_t)(w - (char*)d_ws) > ws_size) {
        fprintf(stderr, "kernel_launch: ws too small: need %zu, have %zu\n",
                (size_t)(w - (char*)d_ws), ws_size);
        return;
    }
    float* out = (float*)d_out;

    const dim3 blk(256);
    auto g64 = [](int M) { return dim3((unsigned)((M + 63) / 64)); };
    const dim3 gEdge((unsigned)((E + 255) / 256));

    // ---------------- ONE kernel splits ALL weights ----------------
    wsplit_all_k<<<dim3(2144), blk, 0, stream>>>(
        g0_Wih, g0_Whh, gWih, gWhh, Wpn, W_et, Wr1, Wr2, W_e1, W_node,
        gwHi, gwLo, wtHi, wtLo, w96Hi, w96Lo);

    // gru with fused dots (wa/wb nullable) + fused pass-3 GEMM (w3 slot)
    auto run_gru = [&](int slot, const float* bih, const float* bhh,
                       const float* wav, const float* wbv,
                       int w3slot, const float* b3, float* out3, int act3) {
        gru_fused_mfma_k<<<g64(N), dim3(512), 0, stream>>>(
            c, gwHi + (size_t)slot * 98304, gwLo + (size_t)slot * 98304,
            bih, bhh, h, wav, wbv, pd, ps,
            wtHi + (size_t)w3slot * 16384, wtLo + (size_t)w3slot * 16384,
            b3, out3, act3, N);
    };
    auto run_mfma128 = [&](const float* A, int slot, const float* bias,
                           float* C, int act) {
        mfma128_k<<<g64(N), dim3(512), 0, stream>>>(
            A, wtHi + (size_t)slot * 16384, wtLo + (size_t)slot * 16384, bias, C, N, act);
    };

    // ---------------- CSR build (graph static across layers) ----------------
    hipMemsetAsync(m_u, 0, (size_t)N * 4, stream);
    hist_k<<<gEdge, blk, 0, stream>>>(dst, m_u, E);
    scan_k<<<dim3(1), dim3(1024), 0, stream>>>(m_u, rp, N);
    hipMemcpyAsync(posb, rp, (size_t)N * 4, hipMemcpyDeviceToDevice, stream);
    fill_csr_k<<<gEdge, blk, 0, stream>>>(dst, src, posb, eidx, srcS, dstS, einv, E);
    bperm_k<<<dim3((unsigned)(((long long)E * 12 + 255) / 256)), blk, 0, stream>>>(
        bond, eidx, bondS, E);
    // graph rowptr from sorted ngid
    hipMemsetAsync(m_u, 0, (size_t)G * 4, stream);
    hist_k<<<dim3((unsigned)((N + 255) / 256)), blk, 0, stream>>>(ngid, m_u, N);
    scan_k<<<dim3(1), dim3(1024), 0, stream>>>(m_u, grp, G);

    // ---------------- GetContext ----------------
    // h = leaky(atom @ W_node + b_node); pd = h . W_e2[0:128]  (fused dot)
    mfma96_k<<<g64(N), dim3(512), 0, stream>>>(
        atom, nullptr, nullptr, nullptr, w96Hi + 12288, w96Lo + 12288, b_node, h,
        W_e2, pd, nullptr, nullptr, nullptr, nullptr, 1, N, 74, ACT_LEAKY);
    // pass A (ONE dispatch over E): pe[e] = he1[e] . W_e2[128:256]
    mfma96_k<<<g64(E), dim3(512), 0, stream>>>(
        atom, bond, src, nullptr, w96Hi, w96Lo, b_e1,
        nullptr, W_e2 + 128, pe, nullptr, nullptr, nullptr, nullptr, 0, E, 74, ACT_LEAKY);
    hipMemsetAsync(m_u, 0, (size_t)N * 4, stream);
    hipMemsetAsync(sden, 0, (size_t)N * 4, stream);
    edge_lgc_k<<<gEdge, blk, 0, stream>>>(pd, pe, b_e2, dst, lg, m_u, E);
    edge_exp_k<<<gEdge, blk, 0, stream>>>(lg, m_u, sden, dst, einv, lgS, E);
    // pass B (CSR order, inputs pre-permuted): segmented softmax-scatter into c
    hipMemsetAsync(c, 0, (size_t)N * 128 * 4, stream);
    mfma96_k<<<g64(E), dim3(512), 0, stream>>>(
        atom, bondS, srcS, nullptr, w96Hi, w96Lo, b_e1,
        nullptr, nullptr, nullptr, lgS, sden, dstS, c, 0, E, 74, ACT_LEAKY);
    run_mfma128(c, 11, b_et, c, ACT_NONE);
    // GRU 0: fused dots Wpe[0] + fused hp = h @ Wpn[0] (pass 3)
    run_gru(0, g0_bih, g0_bhh, Wpe, Wpe + 128, 0, bpn, hp, ACT_NONE);

    // ---------------- 11 GNN layers ----------------
    for (int l = 0; l < L; ++l) {
        layer_gather_k<<<dim3((unsigned)((N + 3) / 4)), blk, 0, stream>>>(
            rp, srcS, pd, ps, bpe + l, hp, c, N);
        const bool more = (l + 1 < L);
        if (more) {
            run_gru(l + 1, gbih + (size_t)l * 384, gbhh + (size_t)l * 384,
                    Wpe + (size_t)(l + 1) * 256, Wpe + (size_t)(l + 1) * 256 + 128,
                    l + 1, bpn + (size_t)(l + 1) * 128, hp, ACT_NONE);
        } else {
            // last GRU: no dots; pass 3 = c = relu(h @ Wr1 + br1)
            run_gru(l + 1, gbih + (size_t)l * 384, gbhh + (size_t)l * 384,
                    nullptr, nullptr, 12, br1, c, ACT_RELU);
        }
    }

    // ---------------- readout ----------------
    run_mfma128(c, 13, br2, hp, ACT_NONE);
    readout_mean_k<<<dim3((unsigned)((G + 3) / 4)), blk, 0, stream>>>(hp, grp, out, G);

    (void)n_in;
}

// Round 25
// 3272.536 us; speedup vs baseline: 1.1759x; 1.1759x over previous
//
#include <hip/hip_runtime.h>
#include <cstdio>
#include <cstddef>

enum { ACT_NONE = 0, ACT_LEAKY = 1, ACT_RELU = 2 };

typedef __attribute__((ext_vector_type(8))) short short8v;
typedef __attribute__((ext_vector_type(4))) float f32x4;

__device__ __forceinline__ float leakyf(float x) { return x > 0.f ? x : 0.01f * x; }

// order-preserving float -> uint encoding for atomicMax
__device__ __forceinline__ unsigned fenc(float f) {
    unsigned u = __float_as_uint(f);
    return (u & 0x80000000u) ? ~u : (u | 0x80000000u);
}
__device__ __forceinline__ float fdec(unsigned u) {
    return (u & 0x80000000u) ? __uint_as_float(u & 0x7FFFFFFFu) : __uint_as_float(~u);
}

// round-to-nearest bf16 (returns low 16 bits)
__device__ __forceinline__ unsigned bf16rtn(float x) {
    unsigned u = __float_as_uint(x);
    return (u + 0x7FFFu + ((u >> 16) & 1u)) >> 16;
}
__device__ __forceinline__ void split8(float4 a, float4 b, short8v& hi, short8v& lo) {
    const float v[8] = {a.x, a.y, a.z, a.w, b.x, b.y, b.z, b.w};
#pragma unroll
    for (int i = 0; i < 8; i++) {
        const unsigned hb = bf16rtn(v[i]);
        const float r = v[i] - __uint_as_float(hb << 16);
        hi[i] = (short)hb;
        lo[i] = (short)bf16rtn(r);
    }
}
__device__ __forceinline__ float eluf(float x) { return x > 0.f ? x : expm1f(x); }

// ---------------------------------------------------------------------------
// ONE kernel splitting ALL weights.
// ---------------------------------------------------------------------------
__global__ __launch_bounds__(256) void wsplit_all_k(
    const float* __restrict__ g0_Wih, const float* __restrict__ g0_Whh,
    const float* __restrict__ gWih,   const float* __restrict__ gWhh,
    const float* __restrict__ Wpn,    const float* __restrict__ W_et,
    const float* __restrict__ Wr1,    const float* __restrict__ Wr2,
    const float* __restrict__ W_e1,   const float* __restrict__ W_node,
    unsigned short* __restrict__ gwHi, unsigned short* __restrict__ gwLo,
    unsigned short* __restrict__ wtHi, unsigned short* __restrict__ wtLo,
    unsigned short* __restrict__ w96Hi, unsigned short* __restrict__ w96Lo)
{
    const int b = blockIdx.x, t = threadIdx.x;
    if (b < 1152) {
        const int slot = b / 96, inner = b % 96;
        const int i4 = (inner * 256 + t) * 4;
        if (i4 >= 98304) return;
        const float* Wih = slot == 0 ? g0_Wih : gWih + (size_t)(slot - 1) * 49152;
        const float* Whh = slot == 0 ? g0_Whh : gWhh + (size_t)(slot - 1) * 49152;
        const float* src = (i4 < 49152) ? (Wih + i4) : (Whh + (i4 - 49152));
        const float4 v = *(const float4*)src;
        const float vv[4] = {v.x, v.y, v.z, v.w};
        unsigned short h4[4], l4[4];
#pragma unroll
        for (int i = 0; i < 4; i++) {
            const unsigned hb = bf16rtn(vv[i]);
            const float r = vv[i] - __uint_as_float(hb << 16);
            h4[i] = (unsigned short)hb;
            l4[i] = (unsigned short)bf16rtn(r);
        }
        *(ushort4*)&gwHi[(size_t)slot * 98304 + i4] = make_ushort4(h4[0], h4[1], h4[2], h4[3]);
        *(ushort4*)&gwLo[(size_t)slot * 98304 + i4] = make_ushort4(l4[0], l4[1], l4[2], l4[3]);
    } else if (b < 2048) {
        const int q = b - 1152;
        const int slot = q / 64, inner = q % 64;
        const int idx = inner * 256 + t;
        if (idx >= 16384) return;
        const float* W = slot < 11 ? Wpn + (size_t)slot * 16384
                        : slot == 11 ? W_et : slot == 12 ? Wr1 : Wr2;
        const int k = idx >> 7, col = idx & 127;
        const float v = W[idx];
        const unsigned hb = bf16rtn(v);
        const float r = v - __uint_as_float(hb << 16);
        wtHi[(size_t)slot * 16384 + col * 128 + k] = (unsigned short)hb;
        wtLo[(size_t)slot * 16384 + col * 128 + k] = (unsigned short)bf16rtn(r);
    } else {
        const int q = b - 2048;
        const int slot = q / 48, inner = q % 48;
        const int idx = inner * 256 + t;
        if (idx >= 12288) return;
        const float* W = slot == 0 ? W_e1 : W_node;
        const int K   = slot == 0 ? 86 : 74;
        const int col = idx / 96, k = idx - col * 96;
        const float v = (k < K) ? W[(size_t)k * 128 + col] : 0.f;
        const unsigned hb = bf16rtn(v);
        const float r = v - __uint_as_float(hb << 16);
        w96Hi[(size_t)slot * 12288 + idx] = (unsigned short)hb;
        w96Lo[(size_t)slot * 12288 + idx] = (unsigned short)bf16rtn(r);
    }
}

// ---------------------------------------------------------------------------
// FUSED GRU via bf16x3 MFMA (round-18/19/22/23 verified structure): 3-barrier
// two-stage core, LDS-transpose dots, fused pass-3 out3 = act3(h_new@W3+b3).
// (round-24 post-mortem: h-prefetch (T14) raised VGPR and cut occupancy ->
// reverted; TLP at 64 VGPR / 8 waves-SIMD already hides stage(h) latency.)
// ---------------------------------------------------------------------------
__global__ __launch_bounds__(512) void gru_fused_mfma_k(
    const float* __restrict__ cbuf, const unsigned short* __restrict__ whi,
    const unsigned short* __restrict__ wlo, const float* __restrict__ bih,
    const float* __restrict__ bhh, float* __restrict__ h,
    const float* __restrict__ wa, const float* __restrict__ wb,
    float* __restrict__ pd, float* __restrict__ ps,
    const unsigned short* __restrict__ w3hi, const unsigned short* __restrict__ w3lo,
    const float* __restrict__ b3, float* __restrict__ out3, int act3, int M)
{
    __shared__ __align__(16) char smem[64 * 132 * 4];   // 33792 B
    short (*lhi)[4][64][8] = (short(*)[4][64][8])smem;              // 16 KB
    short (*llo)[4][64][8] = (short(*)[4][64][8])(smem + 16384);    // 16 KB
    float (*fbuf)[132] = (float(*)[132])smem;                       // overlay

    const int t    = threadIdx.x;
    const int lane = t & 63;
    const int w    = t >> 6;
    const int rBase = blockIdx.x * 64;

    const int sRS = t >> 3, sQ = t & 7;
    const int sRow = rBase + sRS;
    const int sRT = sRS >> 4, sLrow = sRS & 15;

    auto stage = [&](const float* __restrict__ A, bool doElu) {
#pragma unroll
        for (int half = 0; half < 2; half++) {
            const int k0 = sQ * 16 + half * 8;
            const int kc = k0 >> 5;
            const int g  = (k0 & 31) >> 3;
            float4 f0 = make_float4(0.f, 0.f, 0.f, 0.f);
            float4 f1 = make_float4(0.f, 0.f, 0.f, 0.f);
            if (sRow < M) {
                f0 = *(const float4*)&A[(size_t)sRow * 128 + k0];
                f1 = *(const float4*)&A[(size_t)sRow * 128 + k0 + 4];
                if (doElu) {
                    f0.x = eluf(f0.x); f0.y = eluf(f0.y); f0.z = eluf(f0.z); f0.w = eluf(f0.w);
                    f1.x = eluf(f1.x); f1.y = eluf(f1.y); f1.z = eluf(f1.z); f1.w = eluf(f1.w);
                }
            }
            short8v h8, l8;
            split8(f0, f1, h8, l8);
            *(short8v*)&lhi[sRT][kc][sLrow + g * 16][0] = h8;
            *(short8v*)&llo[sRT][kc][sLrow + g * 16][0] = l8;
        }
    };

    f32x4 accr[4], accz[4], accig[4], acchg[4];
#pragma unroll
    for (int rt = 0; rt < 4; rt++) {
        accr[rt]  = (f32x4){0.f, 0.f, 0.f, 0.f};
        accz[rt]  = (f32x4){0.f, 0.f, 0.f, 0.f};
        accig[rt] = (f32x4){0.f, 0.f, 0.f, 0.f};
        acchg[rt] = (f32x4){0.f, 0.f, 0.f, 0.f};
    }

    const int cw   = w * 16 + (lane & 15);   // gate-col [0,128)
    const int koff = (lane >> 4) * 8;

    // ---- pass 1: elu(c) @ Wih.T ----
    stage(cbuf, true);
    __syncthreads();
#pragma unroll
    for (int kc = 0; kc < 4; kc++) {
        short8v bh[3], bl[3];
#pragma unroll
        for (int g = 0; g < 3; g++) {
            const size_t off = (size_t)(g * 128 + cw) * 128 + kc * 32 + koff;
            bh[g] = *(const short8v*)&whi[off];
            bl[g] = *(const short8v*)&wlo[off];
        }
#pragma unroll
        for (int rt = 0; rt < 4; rt++) {
            const short8v ah = *(const short8v*)&lhi[rt][kc][lane][0];
            const short8v al = *(const short8v*)&llo[rt][kc][lane][0];
            accr[rt]  = __builtin_amdgcn_mfma_f32_16x16x32_bf16(ah, bh[0], accr[rt], 0, 0, 0);
            accr[rt]  = __builtin_amdgcn_mfma_f32_16x16x32_bf16(al, bh[0], accr[rt], 0, 0, 0);
            accr[rt]  = __builtin_amdgcn_mfma_f32_16x16x32_bf16(ah, bl[0], accr[rt], 0, 0, 0);
            accz[rt]  = __builtin_amdgcn_mfma_f32_16x16x32_bf16(ah, bh[1], accz[rt], 0, 0, 0);
            accz[rt]  = __builtin_amdgcn_mfma_f32_16x16x32_bf16(al, bh[1], accz[rt], 0, 0, 0);
            accz[rt]  = __builtin_amdgcn_mfma_f32_16x16x32_bf16(ah, bl[1], accz[rt], 0, 0, 0);
            accig[rt] = __builtin_amdgcn_mfma_f32_16x16x32_bf16(ah, bh[2], accig[rt], 0, 0, 0);
            accig[rt] = __builtin_amdgcn_mfma_f32_16x16x32_bf16(al, bh[2], accig[rt], 0, 0, 0);
            accig[rt] = __builtin_amdgcn_mfma_f32_16x16x32_bf16(ah, bl[2], accig[rt], 0, 0, 0);
        }
    }
    __syncthreads();   // all waves done reading LDS before re-stage

    // ---- pass 2: h @ Whh.T (r,z accumulate into same accs) ----
    stage(h, false);
    __syncthreads();
#pragma unroll
    for (int kc = 0; kc < 4; kc++) {
        short8v bh[3], bl[3];
#pragma unroll
        for (int g = 0; g < 3; g++) {
            const size_t off = (size_t)(384 + g * 128 + cw) * 128 + kc * 32 + koff;
            bh[g] = *(const short8v*)&whi[off];
            bl[g] = *(const short8v*)&wlo[off];
        }
#pragma unroll
        for (int rt = 0; rt < 4; rt++) {
            const short8v ah = *(const short8v*)&lhi[rt][kc][lane][0];
            const short8v al = *(const short8v*)&llo[rt][kc][lane][0];
            accr[rt]  = __builtin_amdgcn_mfma_f32_16x16x32_bf16(ah, bh[0], accr[rt], 0, 0, 0);
            accr[rt]  = __builtin_amdgcn_mfma_f32_16x16x32_bf16(al, bh[0], accr[rt], 0, 0, 0);
            accr[rt]  = __builtin_amdgcn_mfma_f32_16x16x32_bf16(ah, bl[0], accr[rt], 0, 0, 0);
            accz[rt]  = __builtin_amdgcn_mfma_f32_16x16x32_bf16(ah, bh[1], accz[rt], 0, 0, 0);
            accz[rt]  = __builtin_amdgcn_mfma_f32_16x16x32_bf16(al, bh[1], accz[rt], 0, 0, 0);
            accz[rt]  = __builtin_amdgcn_mfma_f32_16x16x32_bf16(ah, bl[1], accz[rt], 0, 0, 0);
            acchg[rt] = __builtin_amdgcn_mfma_f32_16x16x32_bf16(ah, bh[2], acchg[rt], 0, 0, 0);
            acchg[rt] = __builtin_amdgcn_mfma_f32_16x16x32_bf16(al, bh[2], acchg[rt], 0, 0, 0);
            acchg[rt] = __builtin_amdgcn_mfma_f32_16x16x32_bf16(ah, bl[2], acchg[rt], 0, 0, 0);
        }
    }

    // ---- gate epilogue ----
    const bool post = (wa != nullptr) || (w3hi != nullptr);
    const float br_  = bih[cw] + bhh[cw];
    const float bz_  = bih[128 + cw] + bhh[128 + cw];
    const float big_ = bih[256 + cw];
    const float bhg_ = bhh[256 + cw];
    if (post) __syncthreads();   // MFMA LDS reads done before fbuf overlay
#pragma unroll
    for (int rt = 0; rt < 4; rt++) {
        const int lr0 = rt * 16 + ((lane >> 4) << 2);
#pragma unroll
        for (int i = 0; i < 4; i++) {
            const int row = rBase + lr0 + i;
            const bool ok = (row < M);
            float hnew = 0.f;
            if (ok) {
                const float hv = h[(size_t)row * 128 + cw];
                const float r  = 1.f / (1.f + expf(-(accr[rt][i] + br_)));
                const float z  = 1.f / (1.f + expf(-(accz[rt][i] + bz_)));
                const float nn = tanhf(accig[rt][i] + big_ + r * (acchg[rt][i] + bhg_));
                hnew = fmaxf((1.f - z) * nn + z * hv, 0.f);
                h[(size_t)row * 128 + cw] = hnew;
            }
            if (post) fbuf[lr0 + i][cw] = hnew;
        }
    }
    if (!post) return;
    __syncthreads();

    // ---- fused node-dots (first 64 threads) ----
    if (wa && t < 64 && rBase + t < M) {
        float accd = 0.f, accs = 0.f;
        for (int cc = 0; cc < 128; cc++) {
            const float hv = fbuf[t][cc];
            accd = fmaf(hv, wa[cc], accd);
            accs = fmaf(hv, wb[cc], accs);
        }
        pd[rBase + t] = accd;
        ps[rBase + t] = accs;
    }

    // ---- pass 3: out3 = act3(h_new @ W3 + b3), h_new re-staged from LDS ----
    if (w3hi) {
        float4 rv[2][2];
#pragma unroll
        for (int half = 0; half < 2; half++) {
            const int k0 = sQ * 16 + half * 8;
            rv[half][0] = *(const float4*)&fbuf[sRS][k0];
            rv[half][1] = *(const float4*)&fbuf[sRS][k0 + 4];
        }
        __syncthreads();   // fbuf reads done before lhi/llo overwrite
#pragma unroll
        for (int half = 0; half < 2; half++) {
            const int k0 = sQ * 16 + half * 8;
            const int kc = k0 >> 5;
            const int g  = (k0 & 31) >> 3;
            short8v h8, l8;
            split8(rv[half][0], rv[half][1], h8, l8);
            *(short8v*)&lhi[sRT][kc][sLrow + g * 16][0] = h8;
            *(short8v*)&llo[sRT][kc][sLrow + g * 16][0] = l8;
        }
        __syncthreads();

        f32x4 acc3[4];
#pragma unroll
        for (int rt = 0; rt < 4; rt++) acc3[rt] = (f32x4){0.f, 0.f, 0.f, 0.f};
#pragma unroll
        for (int kc = 0; kc < 4; kc++) {
            const size_t off = (size_t)cw * 128 + kc * 32 + koff;
            const short8v bh = *(const short8v*)&w3hi[off];
            const short8v bl = *(const short8v*)&w3lo[off];
#pragma unroll
            for (int rt = 0; rt < 4; rt++) {
                const short8v ah = *(const short8v*)&lhi[rt][kc][lane][0];
                const short8v al = *(const short8v*)&llo[rt][kc][lane][0];
                acc3[rt] = __builtin_amdgcn_mfma_f32_16x16x32_bf16(ah, bh, acc3[rt], 0, 0, 0);
                acc3[rt] = __builtin_amdgcn_mfma_f32_16x16x32_bf16(al, bh, acc3[rt], 0, 0, 0);
                acc3[rt] = __builtin_amdgcn_mfma_f32_16x16x32_bf16(ah, bl, acc3[rt], 0, 0, 0);
            }
        }
        const float b0 = b3[cw];
#pragma unroll
        for (int rt = 0; rt < 4; rt++) {
            const int r0 = rBase + rt * 16 + ((lane >> 4) << 2);
#pragma unroll
            for (int i = 0; i < 4; i++) {
                const int row = r0 + i;
                if (row >= M) continue;
                float v = acc3[rt][i] + b0;
                if (act3 == ACT_LEAKY)      v = v > 0.f ? v : 0.01f * v;
                else if (act3 == ACT_RELU)  v = fmaxf(v, 0.f);
                out3[(size_t)row * 128 + cw] = v;
            }
        }
    }
}

// ---------------------------------------------------------------------------
// Single-output MFMA GEMM (K=128, NC=128), bf16x3 (round-13 verified).
// ---------------------------------------------------------------------------
__global__ __launch_bounds__(512) void mfma128_k(
    const float* __restrict__ A, const unsigned short* __restrict__ whi,
    const unsigned short* __restrict__ wlo, const float* __restrict__ bias,
    float* __restrict__ C, int M, int actOut)
{
    __shared__ short lhi[4][4][64][8];
    __shared__ short llo[4][4][64][8];
    const int t    = threadIdx.x;
    const int lane = t & 63;
    const int w    = t >> 6;
    const int rBase = blockIdx.x * 64;

    {
        const int rS = t >> 3, q = t & 7;
        const int row = rBase + rS;
        const int rt = rS >> 4, lrow = rS & 15;
#pragma unroll
        for (int half = 0; half < 2; half++) {
            const int k0 = q * 16 + half * 8;
            const int kc = k0 >> 5;
            const int g  = (k0 & 31) >> 3;
            float4 f0 = make_float4(0.f, 0.f, 0.f, 0.f);
            float4 f1 = make_float4(0.f, 0.f, 0.f, 0.f);
            if (row < M) {
                f0 = *(const float4*)&A[(size_t)row * 128 + k0];
                f1 = *(const float4*)&A[(size_t)row * 128 + k0 + 4];
            }
            short8v h8, l8;
            split8(f0, f1, h8, l8);
            *(short8v*)&lhi[rt][kc][lrow + g * 16][0] = h8;
            *(short8v*)&llo[rt][kc][lrow + g * 16][0] = l8;
        }
    }
    __syncthreads();

    f32x4 acc[4];
#pragma unroll
    for (int rt = 0; rt < 4; rt++) acc[rt] = (f32x4){0.f, 0.f, 0.f, 0.f};

    const int cw   = w * 16 + (lane & 15);
    const int koff = (lane >> 4) * 8;

#pragma unroll
    for (int kc = 0; kc < 4; kc++) {
        const size_t off = (size_t)cw * 128 + kc * 32 + koff;
        const short8v bh = *(const short8v*)&whi[off];
        const short8v bl = *(const short8v*)&wlo[off];
#pragma unroll
        for (int rt = 0; rt < 4; rt++) {
            const short8v ah = *(const short8v*)&lhi[rt][kc][lane][0];
            const short8v al = *(const short8v*)&llo[rt][kc][lane][0];
            acc[rt] = __builtin_amdgcn_mfma_f32_16x16x32_bf16(ah, bh, acc[rt], 0, 0, 0);
            acc[rt] = __builtin_amdgcn_mfma_f32_16x16x32_bf16(al, bh, acc[rt], 0, 0, 0);
            acc[rt] = __builtin_amdgcn_mfma_f32_16x16x32_bf16(ah, bl, acc[rt], 0, 0, 0);
        }
    }

    const float b0 = bias[cw];
#pragma unroll
    for (int rt = 0; rt < 4; rt++) {
        const int r0 = rBase + rt * 16 + ((lane >> 4) << 2);
#pragma unroll
        for (int i = 0; i < 4; i++) {
            const int row = r0 + i;
            if (row >= M) continue;
            float v = acc[rt][i] + b0;
            if (actOut == ACT_LEAKY)      v = v > 0.f ? v : 0.01f * v;
            else if (actOut == ACT_RELU)  v = fmaxf(v, 0.f);
            C[(size_t)row * 128 + cw] = v;
        }
    }
}

// ---------------------------------------------------------------------------
// Gathered MFMA GEMM, K padded to 96. Modes (combinable):
//   writeC : C[row] = v
//   dotOut : dotOut[row] = v . dotW      (LDS transpose-reduce, no atomics)
//   ee     : CSR-ordered fused softmax-scatter with SEGMENTED atomics
//            (ee/sd/dstI indexed by row directly; inputs pre-permuted)
// ---------------------------------------------------------------------------
__global__ __launch_bounds__(512) void mfma96_k(
    const float* __restrict__ A1, const float* __restrict__ A2,
    const int* __restrict__ idx, const int* __restrict__ idx2,
    const unsigned short* __restrict__ whi, const unsigned short* __restrict__ wlo,
    const float* __restrict__ bias, float* __restrict__ C,
    const float* __restrict__ dotW, float* __restrict__ dotOut,
    const float* __restrict__ ee, const float* __restrict__ sd,
    const int* __restrict__ dstI, float* __restrict__ cAtom,
    int writeC, int M, int K1, int actOut)
{
    __shared__ __align__(16) char smem[64 * 130 * 4];   // 33280 B
    short (*lhi)[3][64][8] = (short(*)[3][64][8])smem;              // 12288
    short (*llo)[3][64][8] = (short(*)[3][64][8])(smem + 12288);    // 12288
    float (*fbuf)[130] = (float(*)[130])smem;                       // overlay

    const int t    = threadIdx.x;
    const int lane = t & 63;
    const int w    = t >> 6;
    const int rBase = blockIdx.x * 64;

    {
        const int rS = t >> 3, q = t & 7;
        const int row = rBase + rS;
        const int rt = rS >> 4, lrow = rS & 15;
#pragma unroll
        for (int half = 0; half < 2; half++) {
            const int k0 = q * 16 + half * 8;
            if (k0 >= 96) continue;
            const int kc = k0 >> 5;
            const int g  = (k0 & 31) >> 3;
            float v[8] = {0.f, 0.f, 0.f, 0.f, 0.f, 0.f, 0.f, 0.f};
            if (row < M) {
                const int ar  = idx ? idx[row] : row;
                const int ar2 = idx2 ? idx2[row] : row;
                const float* __restrict__ a1 = A1 + (size_t)ar * K1;
#pragma unroll
                for (int j = 0; j < 8; j++) {
                    const int k = k0 + j;
                    if (k < K1)                 v[j] = a1[k];
                    else if (A2 && k < K1 + 12) v[j] = A2[(size_t)ar2 * 12 + (k - K1)];
                }
            }
            short8v h8, l8;
            split8(make_float4(v[0], v[1], v[2], v[3]),
                   make_float4(v[4], v[5], v[6], v[7]), h8, l8);
            *(short8v*)&lhi[rt][kc][lrow + g * 16][0] = h8;
            *(short8v*)&llo[rt][kc][lrow + g * 16][0] = l8;
        }
    }
    __syncthreads();

    f32x4 acc[4];
#pragma unroll
    for (int rt = 0; rt < 4; rt++) acc[rt] = (f32x4){0.f, 0.f, 0.f, 0.f};

    const int cw   = w * 16 + (lane & 15);
    const int koff = (lane >> 4) * 8;

#pragma unroll
    for (int kc = 0; kc < 3; kc++) {
        const size_t off = (size_t)cw * 96 + kc * 32 + koff;
        const short8v bh = *(const short8v*)&whi[off];
        const short8v bl = *(const short8v*)&wlo[off];
#pragma unroll
        for (int rt = 0; rt < 4; rt++) {
            const short8v ah = *(const short8v*)&lhi[rt][kc][lane][0];
            const short8v al = *(const short8v*)&llo[rt][kc][lane][0];
            acc[rt] = __builtin_amdgcn_mfma_f32_16x16x32_bf16(ah, bh, acc[rt], 0, 0, 0);
            acc[rt] = __builtin_amdgcn_mfma_f32_16x16x32_bf16(al, bh, acc[rt], 0, 0, 0);
            acc[rt] = __builtin_amdgcn_mfma_f32_16x16x32_bf16(ah, bl, acc[rt], 0, 0, 0);
        }
    }

    const float b0 = bias[cw];
    const bool useF = (dotOut != nullptr) || (ee != nullptr);
    if (useF) __syncthreads();   // MFMA LDS reads done before fbuf overlay
#pragma unroll
    for (int rt = 0; rt < 4; rt++) {
        const int lr0 = rt * 16 + ((lane >> 4) << 2);
#pragma unroll
        for (int i = 0; i < 4; i++) {
            const int row = rBase + lr0 + i;
            const bool ok = (row < M);
            float v = acc[rt][i] + b0;
            if (actOut == ACT_LEAKY)      v = v > 0.f ? v : 0.01f * v;
            else if (actOut == ACT_RELU)  v = fmaxf(v, 0.f);
            if (ok && writeC) C[(size_t)row * 128 + cw] = v;
            if (ee) {
                float av = 0.f;
                if (ok) av = ee[row] / sd[dstI[row]] * v;
                fbuf[lr0 + i][cw] = av;
            } else if (dotOut) {
                fbuf[lr0 + i][cw] = ok ? v : 0.f;
            }
        }
    }
    if (ee) {
        __syncthreads();
        // segmented run-length reduce: thread owns col (t&127), rows (t>>7)*16..+15
        const int col = t & 127;
        const int r0  = (t >> 7) * 16;
        float acc2 = 0.f;
        int cur = -1;
        for (int j = 0; j < 16; j++) {
            const int row = rBase + r0 + j;
            if (row >= M) break;
            const int d = dstI[row];
            if (d != cur) {
                if (cur >= 0) atomicAdd(&cAtom[(size_t)cur * 128 + col], acc2);
                cur = d;
                acc2 = 0.f;
            }
            acc2 += fbuf[r0 + j][col];
        }
        if (cur >= 0) atomicAdd(&cAtom[(size_t)cur * 128 + col], acc2);
    } else if (dotOut) {
        __syncthreads();
        if (t < 64 && rBase + t < M) {
            float accd = 0.f;
            for (int cc = 0; cc < 128; cc++)
                accd = fmaf(fbuf[t][cc], dotW[cc], accd);
            dotOut[rBase + t] = accd;
        }
    }
}

// GetContext edge logits from precomputed pe: lg = leaky(pd[dst]+pe[e]+b2); atomicMax m
__global__ __launch_bounds__(256) void edge_lgc_k(
    const float* __restrict__ pd, const float* __restrict__ pe,
    const float* __restrict__ b2, const int* __restrict__ dst,
    float* __restrict__ lg, unsigned* __restrict__ m_u, int E)
{
    const int e = blockIdx.x * blockDim.x + threadIdx.x;
    if (e >= E) return;
    const int d = dst[e];
    const float v = leakyf(pd[d] + pe[e] + b2[0]);
    lg[e] = v;
    atomicMax(&m_u[d], fenc(v));
}

// ex = exp(lg - m[dst]); s[dst] += ex; lgS[einv[e]] = ex  (sorted-order copy)
__global__ __launch_bounds__(256) void edge_exp_k(
    const float* __restrict__ lg, const unsigned* __restrict__ m_u,
    float* __restrict__ s, const int* __restrict__ dst,
    const int* __restrict__ einv, float* __restrict__ lgS, int E)
{
    const int e = blockIdx.x * blockDim.x + threadIdx.x;
    if (e >= E) return;
    const int d = dst[e];
    const float ex = expf(lg[e] - fdec(m_u[d]));
    lgS[einv[e]] = ex;
    atomicAdd(&s[d], ex);
}

// permute bond rows into CSR (dst-sorted) order: bondS[p] = bond[eidx[p]]
__global__ __launch_bounds__(256) void bperm_k(
    const float* __restrict__ bond, const int* __restrict__ eidx,
    float* __restrict__ bondS, int E)
{
    const long long i = (long long)blockIdx.x * blockDim.x + threadIdx.x;
    if (i >= (long long)E * 12) return;
    const int p = (int)(i / 12), j = (int)(i - (long long)p * 12);
    bondS[i] = bond[(size_t)eidx[p] * 12 + j];
}

// ---------------------------------------------------------------------------
// CSR build: histogram -> exclusive scan -> fill (emits srcS/dstS/einv)
// ---------------------------------------------------------------------------
__global__ __launch_bounds__(256) void hist_k(
    const int* __restrict__ dst, unsigned* __restrict__ cnt, int E)
{
    const int e = blockIdx.x * blockDim.x + threadIdx.x;
    if (e < E) atomicAdd(&cnt[dst[e]], 1u);
}

__global__ __launch_bounds__(1024) void scan_k(
    const unsigned* __restrict__ cnt, int* __restrict__ rp, int N)
{
    __shared__ int wsum[16];
    __shared__ int carry;
    const int t = threadIdx.x, lane = t & 63, wid = t >> 6;
    if (t == 0) carry = 0;
    __syncthreads();
    for (int base = 0; base < N; base += 1024) {
        const int i = base + t;
        const int v = (i < N) ? (int)cnt[i] : 0;
        int x = v;
#pragma unroll
        for (int o = 1; o < 64; o <<= 1) {
            const int y = __shfl_up(x, o, 64);
            if (lane >= o) x += y;
        }
        if (lane == 63) wsum[wid] = x;
        __syncthreads();
        if (wid == 0) {
            const int wv = (lane < 16) ? wsum[lane] : 0;
            int wx = wv;
#pragma unroll
            for (int o = 1; o < 16; o <<= 1) {
                const int y = __shfl_up(wx, o, 64);
                if (lane >= o) wx += y;
            }
            if (lane < 16) wsum[lane] = wx - wv;   // exclusive wave offsets
        }
        __syncthreads();
        const int excl = carry + wsum[wid] + x - v;
        if (i < N) rp[i] = excl;
        __syncthreads();
        if (t == 1023) carry = excl + v;
        __syncthreads();
    }
    if (t == 0) rp[N] = carry;
}

__global__ __launch_bounds__(256) void fill_csr_k(
    const int* __restrict__ dst, const int* __restrict__ src,
    int* __restrict__ pos, int* __restrict__ eidx,
    int* __restrict__ srcS, int* __restrict__ dstS,
    int* __restrict__ einv, int E)
{
    const int e = blockIdx.x * blockDim.x + threadIdx.x;
    if (e < E) {
        const int d = dst[e];
        const int p = atomicAdd(&pos[d], 1);
        eidx[p] = e;
        srcS[p] = src[e];
        dstS[p] = d;
        einv[e] = p;
    }
}

// ---------------------------------------------------------------------------
// Fused per-node edge softmax + weighted gather (layers) -- standalone
// ---------------------------------------------------------------------------
__global__ __launch_bounds__(256) void layer_gather_k(
    const int* __restrict__ rp, const int* __restrict__ srcS,
    const float* __restrict__ pd, const float* __restrict__ ps,
    const float* __restrict__ bpe,
    const float* __restrict__ hp, float* __restrict__ c, int N)
{
    const int d = blockIdx.x * 4 + (threadIdx.x >> 6);
    const int l = threadIdx.x & 63;
    if (d >= N) return;
    const int beg = rp[d], end = rp[d + 1];
    float acc0 = 0.f, acc1 = 0.f;
    if (beg < end) {
        const float pdd = pd[d];
        const float b   = bpe[0];
        float m = -3.4e38f;
        for (int e = beg + l; e < end; e += 64)
            m = fmaxf(m, leakyf(pdd + ps[srcS[e]] + b));
#pragma unroll
        for (int o = 32; o; o >>= 1) m = fmaxf(m, __shfl_xor(m, o, 64));
        float s = 0.f;
        for (int e = beg + l; e < end; e += 64)
            s += expf(leakyf(pdd + ps[srcS[e]] + b) - m);
#pragma unroll
        for (int o = 32; o; o >>= 1) s += __shfl_xor(s, o, 64);
        const float inv = 1.f / s;
        for (int e = beg; e < end; ++e) {
            const int sr = srcS[e];                      // uniform -> broadcast
            const float a = expf(leakyf(pdd + ps[sr] + b) - m) * inv;
            const float2 v = *(const float2*)&hp[(size_t)sr * 128 + l * 2];
            acc0 = fmaf(a, v.x, acc0);
            acc1 = fmaf(a, v.y, acc1);
        }
    }
    *(float2*)&c[(size_t)d * 128 + l * 2] = make_float2(acc0, acc1);
}

// segmented mean readout (node_graph_ids sorted): one wave per graph
__global__ __launch_bounds__(256) void readout_mean_k(
    const float* __restrict__ x, const int* __restrict__ grp,
    float* __restrict__ out, int G)
{
    const int g = blockIdx.x * 4 + (threadIdx.x >> 6);
    const int l = threadIdx.x & 63;
    if (g >= G) return;
    const int beg = grp[g], end = grp[g + 1];
    float s0 = 0.f, s1 = 0.f;
    for (int r = beg; r < end; ++r) {
        const float2 v = *(const float2*)&x[(size_t)r * 128 + l * 2];
        s0 += v.x;
        s1 += v.y;
    }
    const float inv = 1.f / fmaxf((float)(end - beg), 1.f);
    *(float2*)&out[(size_t)g * 128 + l * 2] = make_float2(s0 * inv, s1 * inv);
}

// ---------------------------------------------------------------------------
extern "C" void kernel_launch(void* const* d_in, const int* in_sizes, int n_in,
                              void* d_out, int out_size, void* d_ws, size_t ws_size,
                              hipStream_t stream)
{
    const float* atom   = (const float*)d_in[0];
    const float* bond   = (const float*)d_in[1];
    const int*   src    = (const int*)d_in[2];
    const int*   dst    = (const int*)d_in[3];
    const int*   ngid   = (const int*)d_in[4];
    const float* W_node = (const float*)d_in[5];
    const float* b_node = (const float*)d_in[6];
    const float* W_e1   = (const float*)d_in[7];
    const float* b_e1   = (const float*)d_in[8];
    const float* W_e2   = (const float*)d_in[9];
    const float* b_e2   = (const float*)d_in[10];
    const float* W_et   = (const float*)d_in[11];
    const float* b_et   = (const float*)d_in[12];
    const float* g0_Wih = (const float*)d_in[13];
    const float* g0_bih = (const float*)d_in[14];
    const float* g0_Whh = (const float*)d_in[15];
    const float* g0_bhh = (const float*)d_in[16];
    const float* Wpe    = (const float*)d_in[17];
    const float* bpe    = (const float*)d_in[18];
    const float* Wpn    = (const float*)d_in[19];
    const float* bpn    = (const float*)d_in[20];
    const float* gWih   = (const float*)d_in[21];
    const float* gbih   = (const float*)d_in[22];
    const float* gWhh   = (const float*)d_in[23];
    const float* gbhh   = (const float*)d_in[24];
    const float* Wr1    = (const float*)d_in[25];
    const float* br1    = (const float*)d_in[26];
    const float* Wr2    = (const float*)d_in[27];
    const float* br2    = (const float*)d_in[28];

    const int N = in_sizes[0] / 74;
    const int E = in_sizes[1] / 12;
    const int G = out_size / 128;
    const int L = in_sizes[18];   // bpe is [L][1]

    char* w = (char*)d_ws;
    auto align256 = [](size_t b) { return (b + 255) & ~(size_t)255; };
    auto alloc = [&](size_t bytes) {
        void* p = (void*)w;
        w += align256(bytes);
        return p;
    };
    float*    h    = (float*)alloc((size_t)N * 128 * 4);
    float*    c    = (float*)alloc((size_t)N * 128 * 4);
    float*    hp   = (float*)alloc((size_t)N * 128 * 4);
    int*      rp   = (int*)alloc((size_t)(N + 1) * 4);
    int*      posb = (int*)alloc((size_t)N * 4);
    int*      eidx = (int*)alloc((size_t)E * 4);
    int*      srcS = (int*)alloc((size_t)E * 4);
    int*      dstS = (int*)alloc((size_t)E * 4);
    int*      einv = (int*)alloc((size_t)E * 4);
    float*    bondS= (float*)alloc((size_t)E * 12 * 4);
    float*    lgS  = (float*)alloc((size_t)E * 4);
    int*      grp  = (int*)alloc((size_t)(G + 1) * 4);
    // weight slots: GRU 12 x 98304, T128 14 x 16384, T96 2 x 12288
    unsigned short* gwHi  = (unsigned short*)alloc((size_t)12 * 98304 * 2);
    unsigned short* gwLo  = (unsigned short*)alloc((size_t)12 * 98304 * 2);
    unsigned short* wtHi  = (unsigned short*)alloc((size_t)14 * 16384 * 2);
    unsigned short* wtLo  = (unsigned short*)alloc((size_t)14 * 16384 * 2);
    unsigned short* w96Hi = (unsigned short*)alloc((size_t)2 * 12288 * 2);
    unsigned short* w96Lo = (unsigned short*)alloc((size_t)2 * 12288 * 2);
    float*    pd   = (float*)alloc((size_t)N * 4);
    float*    ps   = (float*)alloc((size_t)N * 4);
    unsigned* m_u  = (unsigned*)alloc((size_t)N * 4);
    float*    sden = (float*)alloc((size_t)N * 4);
    float*    pe   = (float*)alloc((size_t)E * 4);
    float*    lg   = (float*)alloc((size_t)E * 4);
    if ((size_t)(w - (char*)d_ws) > ws_size) {
        fprintf(stderr, "kernel_launch: ws too small: need %zu, have %zu\n",
                (size_t)(w - (char*)d_ws), ws_size);
        return;
    }
    float* out = (float*)d_out;

    const dim3 blk(256);
    auto g64 = [](int M) { return dim3((unsigned)((M + 63) / 64)); };
    const dim3 gEdge((unsigned)((E + 255) / 256));

    // ---------------- ONE kernel splits ALL weights ----------------
    wsplit_all_k<<<dim3(2144), blk, 0, stream>>>(
        g0_Wih, g0_Whh, gWih, gWhh, Wpn, W_et, Wr1, Wr2, W_e1, W_node,
        gwHi, gwLo, wtHi, wtLo, w96Hi, w96Lo);

    // gru with fused dots (wa/wb nullable) + fused pass-3 GEMM (w3 slot)
    auto run_gru = [&](int slot, const float* bih, const float* bhh,
                       const float* wav, const float* wbv,
                       int w3slot, const float* b3, float* out3, int act3) {
        gru_fused_mfma_k<<<g64(N), dim3(512), 0, stream>>>(
            c, gwHi + (size_t)slot * 98304, gwLo + (size_t)slot * 98304,
            bih, bhh, h, wav, wbv, pd, ps,
            wtHi + (size_t)w3slot * 16384, wtLo + (size_t)w3slot * 16384,
            b3, out3, act3, N);
    };
    auto run_mfma128 = [&](const float* A, int slot, const float* bias,
                           float* C, int act) {
        mfma128_k<<<g64(N), dim3(512), 0, stream>>>(
            A, wtHi + (size_t)slot * 16384, wtLo + (size_t)slot * 16384, bias, C, N, act);
    };

    // ---------------- CSR build (graph static across layers) ----------------
    hipMemsetAsync(m_u, 0, (size_t)N * 4, stream);
    hist_k<<<gEdge, blk, 0, stream>>>(dst, m_u, E);
    scan_k<<<dim3(1), dim3(1024), 0, stream>>>(m_u, rp, N);
    hipMemcpyAsync(posb, rp, (size_t)N * 4, hipMemcpyDeviceToDevice, stream);
    fill_csr_k<<<gEdge, blk, 0, stream>>>(dst, src, posb, eidx, srcS, dstS, einv, E);
    bperm_k<<<dim3((unsigned)(((long long)E * 12 + 255) / 256)), blk, 0, stream>>>(
        bond, eidx, bondS, E);
    // graph rowptr from sorted ngid
    hipMemsetAsync(m_u, 0, (size_t)G * 4, stream);
    hist_k<<<dim3((unsigned)((N + 255) / 256)), blk, 0, stream>>>(ngid, m_u, N);
    scan_k<<<dim3(1), dim3(1024), 0, stream>>>(m_u, grp, G);

    // ---------------- GetContext ----------------
    // h = leaky(atom @ W_node + b_node); pd = h . W_e2[0:128]  (fused dot)
    mfma96_k<<<g64(N), dim3(512), 0, stream>>>(
        atom, nullptr, nullptr, nullptr, w96Hi + 12288, w96Lo + 12288, b_node, h,
        W_e2, pd, nullptr, nullptr, nullptr, nullptr, 1, N, 74, ACT_LEAKY);
    // pass A (ONE dispatch over E): pe[e] = he1[e] . W_e2[128:256]
    mfma96_k<<<g64(E), dim3(512), 0, stream>>>(
        atom, bond, src, nullptr, w96Hi, w96Lo, b_e1,
        nullptr, W_e2 + 128, pe, nullptr, nullptr, nullptr, nullptr, 0, E, 74, ACT_LEAKY);
    hipMemsetAsync(m_u, 0, (size_t)N * 4, stream);
    hipMemsetAsync(sden, 0, (size_t)N * 4, stream);
    edge_lgc_k<<<gEdge, blk, 0, stream>>>(pd, pe, b_e2, dst, lg, m_u, E);
    edge_exp_k<<<gEdge, blk, 0, stream>>>(lg, m_u, sden, dst, einv, lgS, E);
    // pass B (CSR order, inputs pre-permuted): segmented softmax-scatter into c
    hipMemsetAsync(c, 0, (size_t)N * 128 * 4, stream);
    mfma96_k<<<g64(E), dim3(512), 0, stream>>>(
        atom, bondS, srcS, nullptr, w96Hi, w96Lo, b_e1,
        nullptr, nullptr, nullptr, lgS, sden, dstS, c, 0, E, 74, ACT_LEAKY);
    run_mfma128(c, 11, b_et, c, ACT_NONE);
    // GRU 0: fused dots Wpe[0] + fused hp = h @ Wpn[0] (pass 3)
    run_gru(0, g0_bih, g0_bhh, Wpe, Wpe + 128, 0, bpn, hp, ACT_NONE);

    // ---------------- 11 GNN layers ----------------
    for (int l = 0; l < L; ++l) {
        layer_gather_k<<<dim3((unsigned)((N + 3) / 4)), blk, 0, stream>>>(
            rp, srcS, pd, ps, bpe + l, hp, c, N);
        const bool more = (l + 1 < L);
        if (more) {
            run_gru(l + 1, gbih + (size_t)l * 384, gbhh + (size_t)l * 384,
                    Wpe + (size_t)(l + 1) * 256, Wpe + (size_t)(l + 1) * 256 + 128,
                    l + 1, bpn + (size_t)(l + 1) * 128, hp, ACT_NONE);
        } else {
            // last GRU: no dots; pass 3 = c = relu(h @ Wr1 + br1)
            run_gru(l + 1, gbih + (size_t)l * 384, gbhh + (size_t)l * 384,
                    nullptr, nullptr, 12, br1, c, ACT_RELU);
        }
    }

    // ---------------- readout ----------------
    run_mfma128(c, 13, br2, hp, ACT_NONE);
    readout_mean_k<<<dim3((unsigned)((G + 3) / 4)), blk, 0, stream>>>(hp, grp, out, G);

    (void)n_in;
}